// Round 12
// baseline (124.207 us; speedup 1.0000x reference)
//
#include <hip/hip_runtime.h>
#include <math.h>

// ROI Align, fused taps form. B=2, K=128, C=256, IMG=512, OH=OW=16.
// Inputs: bboxess[B,K,4] f32, counts[B,1] i32, p2..p5 f32 pyramids, p6 unused.
// Output: f32 [B,K,C,16,16].
// R6: 77us latency-bound. R7: Occ 49%, 70us -> gather tag-pipe bound.
// R8: LDS-stage touched region -> ~30us; DS byte floor ~20us, write 10.5us.
// R9: CSPLIT 16 (LDS 15.4KB -> 8 blocks/CU, 100% occ), flattened full-lane
// staging (small-region blocks: 32 iters -> 1), 2-channel unrolled interp.

constexpr int Bn = 2, Kn = 128, Cn = 256;
constexpr int CSPLIT = 16;           // channel-split blocks per box
constexpr int CCH = Cn / CSPLIT;     // 16 channels per block
constexpr int MAXPX = 240;           // >= max ey*ex_pad (bound: 47x5, 25x9, 14x15)

__device__ __forceinline__ float levelg(int F, int psize) {
  return fmaxf(((float)F + 0.5f) * (float)psize * (1.0f / 512.0f) - 0.5f, 0.0f);
}

__device__ __forceinline__ void to_level(int F, int psize,
                                         int& g0i, int& g1i, float& v) {
  float g = levelg(F, psize);
  float g0 = floorf(g);
  v = g - g0;
  g0i = (int)g0;
  g1i = min(g0i + 1, psize - 1);
}

// x variant: adjacent pair [base, base+1]; edge clamp shifts base to psize-2
// with weights (0,1) -> bit-equivalent to ref's duplicated-tap form.
__device__ __forceinline__ void to_level_pair(int F, int psize,
                                              int& base, float& wlo, float& whi) {
  float g = levelg(F, psize);
  float g0 = floorf(g);
  float v = g - g0;
  int g0i = (int)g0;
  if (g0i >= psize - 1) { base = psize - 2; wlo = 0.0f; whi = 1.0f; }
  else                  { base = g0i;       wlo = 1.0f - v; whi = v; }
}

__device__ __forceinline__ int pair_base(int F, int psize) {
  return min((int)floorf(levelg(F, psize)), psize - 2);
}

__device__ __forceinline__ void bin_f(int o, int crop,
                                      int& f0i, int& f1i, float& w1) {
  float s = fmaxf(((float)o + 0.5f) * (float)crop * (1.0f / 16.0f) - 0.5f, 0.0f);
  float f0 = floorf(s);
  w1 = s - f0;
  f0i = (int)f0;
  f1i = min(f0i + 1, crop - 1);
}

__device__ __forceinline__ float2 load_f2(const float* p) {
  float2 v;
  __builtin_memcpy(&v, p, 8);
  return v;
}

__global__ __launch_bounds__(256, 8)
void roialign_kernel(const float* __restrict__ bbox,
                     const int* __restrict__ counts,
                     const float* __restrict__ p2,
                     const float* __restrict__ p3,
                     const float* __restrict__ p4,
                     const float* __restrict__ p5,
                     float* __restrict__ out) {
  __shared__ float smem[CCH * MAXPX];          // 15.36 KB -> 8 blocks/CU

  const int blk = blockIdx.x;
  const int cpart = blk & (CSPLIT - 1);
  const int box = blk / CSPLIT;                // 0..255 = b*Kn + k
  const int b = box >> 7;
  const int k = box & 127;
  const int t = threadIdx.x;                   // 0..255 = oy*16 + ox
  const int oy = t >> 4, ox = t & 15;

  const long outBase = ((long)box * Cn + cpart * CCH) * 256 + t;

  if (k >= counts[b]) {                        // block-uniform branch
#pragma unroll 4
    for (int c = 0; c < CCH; ++c) out[outBase + (long)c * 256] = 0.0f;
    return;
  }

  // ---- per-box parameters ----
  const float y1f = bbox[box * 4 + 0], x1f = bbox[box * 4 + 1];
  const float y2f = bbox[box * 4 + 2], x2f = bbox[box * 4 + 3];
  const float area = (y2f - y1f) * (x2f - x1f);
  // lvl = clip(round(0.5*log2(area)-3),2,5)-2 via exact half-even thresholds
  const int lvl = (area > 2048.0f) + (area >= 8192.0f) + (area > 32768.0f);
  const int ph = 128 >> lvl;                   // plane is square
  const int pw = ph;

  const int y1 = min(max((int)rintf(y1f), 0), 511);
  const int x1 = min(max((int)rintf(x1f), 0), 511);
  const int y2 = min(max((int)rintf(y2f), y1 + 1), 512);
  const int x2 = min(max((int)rintf(x2f), x1 + 1), 512);
  const int cropy = y2 - y1, cropx = x2 - x1;

  // ---- this thread's y taps: 4 (row, weight) ----
  int iyr[4];
  float wyr[4];
  {
    int f0i, f1i; float w1;
    bin_f(oy, cropy, f0i, f1i, w1);
    int a0, a1, b0, b1; float va, vb;
    to_level(y1 + f0i, ph, a0, a1, va);
    to_level(y1 + f1i, ph, b0, b1, vb);
    iyr[0] = a0; iyr[1] = a1; iyr[2] = b0; iyr[3] = b1;
    wyr[0] = (1.0f - w1) * (1.0f - va);
    wyr[1] = (1.0f - w1) * va;
    wyr[2] = w1 * (1.0f - vb);
    wyr[3] = w1 * vb;
  }

  // ---- this thread's x taps: 2 adjacent pairs ----
  int bx[2];
  float wxl[2], wxh[2];
  {
    int f0i, f1i; float w1;
    bin_f(ox, cropx, f0i, f1i, w1);
    float l0, h0, l1, h1;
    to_level_pair(x1 + f0i, pw, bx[0], l0, h0);
    to_level_pair(x1 + f1i, pw, bx[1], l1, h1);
    wxl[0] = (1.0f - w1) * l0; wxh[0] = (1.0f - w1) * h0;
    wxl[1] = w1 * l1;          wxh[1] = w1 * h1;
  }

  // ---- block-uniform touched region (taps are monotone in oy/ox) ----
  int y_lo, y_hi, x_lo, x_hi;
  {
    int f0a, f1a, f0b, f1b; float wd;
    bin_f(0, cropy, f0a, f1a, wd);
    bin_f(15, cropy, f0b, f1b, wd);
    int g0, g1; float vd;
    to_level(y1 + f0a, ph, g0, g1, vd); y_lo = g0;
    to_level(y1 + f1b, ph, g0, g1, vd); y_hi = g1;
    bin_f(0, cropx, f0a, f1a, wd);
    bin_f(15, cropx, f0b, f1b, wd);
    x_lo = pair_base(x1 + f0a, pw);
    x_hi = pair_base(x1 + f1b, pw) + 1;
  }
  const int ey = y_hi - y_lo + 1;
  const int ex = x_hi - x_lo + 1;              // >= 2
  const int ex_pad = ex | 1;                   // odd stride -> bank spread
  const int region = ey * ex;

  const float* Pbase;
  switch (lvl) {
    case 0: Pbase = p2; break;
    case 1: Pbase = p3; break;
    case 2: Pbase = p4; break;
    default: Pbase = p5; break;                // unreachable for this dist
  }
  const int planeStride = ph * pw;
  const float* plane = Pbase + ((long)b * Cn + cpart * CCH) * planeStride;

  if (ey * ex_pad > MAXPX) {
    // Safety fallback (unreachable by bound analysis): direct global gathers.
    int off[8];
    float wl[8], wh[8];
#pragma unroll
    for (int r = 0; r < 4; ++r)
#pragma unroll
      for (int p = 0; p < 2; ++p) {
        off[r * 2 + p] = iyr[r] * pw + bx[p];
        wl[r * 2 + p] = wyr[r] * wxl[p];
        wh[r * 2 + p] = wyr[r] * wxh[p];
      }
    for (int c = 0; c < CCH; ++c) {
      const float* __restrict__ P = plane + (long)c * planeStride;
      float acc = 0.0f;
#pragma unroll
      for (int i = 0; i < 8; ++i) {
        const float2 v = load_f2(P + off[i]);
        acc = fmaf(wl[i], v.x, acc);
        acc = fmaf(wh[i], v.y, acc);
      }
      out[outBase + (long)c * 256] = acc;
    }
    return;
  }

  // ---- stage region, flattened over (channel, pixel): all 256 lanes busy --
  {
    const int total = region * CCH;            // <= 235*16 = 3760
    for (int e = t; e < total; e += 256) {
      const int c = e / region;                // block-uniform divisor
      const int px = e - c * region;
      const int sr = px / ex;
      const int sx = px - sr * ex;
      smem[c * MAXPX + sr * ex_pad + sx] =
          plane[(long)c * planeStride + (y_lo + sr) * pw + (x_lo + sx)];
    }
  }
  __syncthreads();

  // ---- LDS word-offsets for this thread's 8 tap-pairs ----
  int loff[8];
  float wl[8], wh[8];
#pragma unroll
  for (int r = 0; r < 4; ++r)
#pragma unroll
    for (int p = 0; p < 2; ++p) {
      loff[r * 2 + p] = (iyr[r] - y_lo) * ex_pad + (bx[p] - x_lo);
      wl[r * 2 + p] = wyr[r] * wxl[p];
      wh[r * 2 + p] = wyr[r] * wxh[p];
    }

  // ---- interpolate from LDS, 2 channels per iter for DS ILP ----
  // (per-channel FP order identical to R6-R8: r-major, lo then hi)
  for (int c = 0; c < CCH; c += 2) {
    const float* __restrict__ b0 = smem + c * MAXPX;
    const float* __restrict__ b1 = b0 + MAXPX;
    float a0 = 0.0f, a1 = 0.0f;
#pragma unroll
    for (int i = 0; i < 8; ++i) {
      a0 = fmaf(wl[i], b0[loff[i]], a0);
      a0 = fmaf(wh[i], b0[loff[i] + 1], a0);
      a1 = fmaf(wl[i], b1[loff[i]], a1);
      a1 = fmaf(wh[i], b1[loff[i] + 1], a1);
    }
    out[outBase + (long)c * 256] = a0;
    out[outBase + (long)(c + 1) * 256] = a1;
  }
}

extern "C" void kernel_launch(void* const* d_in, const int* in_sizes, int n_in,
                              void* d_out, int out_size, void* d_ws, size_t ws_size,
                              hipStream_t stream) {
  const float* bbox = (const float*)d_in[0];
  const int* counts = (const int*)d_in[1];
  const float* p2 = (const float*)d_in[2];
  const float* p3 = (const float*)d_in[3];
  const float* p4 = (const float*)d_in[4];
  const float* p5 = (const float*)d_in[5];
  float* out = (float*)d_out;

  dim3 grid(Bn * Kn * CSPLIT);
  dim3 block(256);
  roialign_kernel<<<grid, block, 0, stream>>>(bbox, counts, p2, p3, p4, p5, out);
}